// Round 10
// baseline (98.029 us; speedup 1.0000x reference)
//
#include <hip/hip_runtime.h>
#include <hip/hip_bf16.h>

typedef float f32x4 __attribute__((ext_vector_type(4)));
typedef short s16x8 __attribute__((ext_vector_type(8)));

#define D_DIM 4096
#define NT 24            // 16-wide col tiles (global)
#define BM 128           // rows per block
#define NBODY 32         // bodies per block, BK=32 (one W slab each)
// LDS byte offsets: B[2][24576] @ 0, A[2][8192] @ 49152 -> 64 KiB total
#define BOFF 0
#define AOFF 49152
// ws byte offsets
#define SINW_OFF 3145728u                 // sinws[4][8192] f32 = 128 KiB
#define PART_OFF 3276800u                 // part[4][8192][384] f16 = 24 MiB

__device__ __forceinline__ unsigned short f2bf(float f) {
    unsigned u = __float_as_uint(f);
    u += 0x7fffu + ((u >> 16) & 1u);   // RNE
    return (unsigned short)(u >> 16);
}

__device__ __forceinline__ void gload16(const void* g, void* l) {
    __builtin_amdgcn_global_load_lds(
        (const __attribute__((address_space(1))) unsigned int*)g,
        (__attribute__((address_space(3))) unsigned int*)l, 16, 0, 0);
}

__global__ __launch_bounds__(64) void reg_init_kernel(const float* __restrict__ C,
                                                      const float* __restrict__ Csin,
                                                      float* __restrict__ reg_out) {
    if (threadIdx.x == 0)
        reg_out[0] = 0.05f * (fabsf(C[0]) + fabsf(C[1]) + fabsf(C[2]) + fabsf(Csin[0]));
}

// Build W [4096 x 384] bf16, MFMA B-fragment-packed, slab-contiguous:
// chunk = (k>>5)*NT + (n>>4); lane = ((k&31)>>3)*16 | (n&15); j = k&7.
// Slab s (32 k's) = bytes [s*24576, (s+1)*24576), 24 chunks of 1 KB.
__global__ __launch_bounds__(64) void build_w_kernel(const float* __restrict__ U1,
                                                     const float* __restrict__ U2,
                                                     const float* __restrict__ U3,
                                                     unsigned short* __restrict__ W,
                                                     float* __restrict__ reg_out) {
    const int ks = blockIdx.x / NT;
    const int ct = blockIdx.x % NT;
    const int l  = threadIdx.x;
    const int n  = ct * 16 + (l & 15);
    const int kb = ks * 32 + ((l >> 4) << 3);

    const float* src;
    float scale;
    if (n < 64)       { src = U1 + n;                  scale = 0.01f / 262144.f; }
    else if (n < 128) { src = U2 + (n - 64);           scale = 0.01f / 524288.f; }
    else if (n < 192) { src = U2 + 262144 + (n - 128); scale = 0.01f / 524288.f; }
    else if (n < 256) { src = U3 + (n - 192);          scale = 0.01f / 786432.f; }
    else if (n < 320) { src = U3 + 262144 + (n - 256); scale = 0.01f / 786432.f; }
    else              { src = U3 + 524288 + (n - 320); scale = 0.01f / 786432.f; }

    unsigned short h[8];
    float sabs = 0.f;
#pragma unroll
    for (int j = 0; j < 8; ++j) {
        float u = src[(size_t)(kb + j) * 64];
        sabs += fabsf(u);
        h[j] = f2bf(u);
    }
    uint4 pk;
    pk.x = (unsigned)h[0] | ((unsigned)h[1] << 16);
    pk.y = (unsigned)h[2] | ((unsigned)h[3] << 16);
    pk.z = (unsigned)h[4] | ((unsigned)h[5] << 16);
    pk.w = (unsigned)h[6] | ((unsigned)h[7] << 16);
    *(uint4*)(W + ((size_t)blockIdx.x * 64 + l) * 8) = pk;

    sabs *= scale;
#pragma unroll
    for (int off = 32; off >= 1; off >>= 1)
        sabs += __shfl_xor(sabs, off, 64);
    if (l == 0) atomicAdd(reg_out, sabs);
}

// grid 256 = (rb 0..63) x (ks 0..3); 1024 thr = 16 waves = 2 rg x 8 cg.
// Block: 128 rows x 384 cols x 1024 k, 32 bodies of BK=32. B slabs (24 KB,
// frag-packed contiguous) stream via global_load_lds (zero VGPR cost); only
// acc lives in registers. Per body: issue B(d+1) gload_lds + X(d+2) reg load,
// stage A(d+1) (sin+cvt, ds_write_b64), ds_read 4 A-frags + 3 B-frags,
// lgkm-only wall, 12 MFMA, then vmcnt(1) (drain own B(d+1) chunks, X stays
// in flight) + raw s_barrier. Counted vmcnt -- never 0 in the loop.
__global__ __launch_bounds__(1024, 4) void poly_main_kernel(const float* __restrict__ X,
                                                            const unsigned short* __restrict__ W,
                                                            _Float16* __restrict__ part,
                                                            float* __restrict__ sinws) {
    __shared__ __align__(16) char pool[65536];

    const int t    = threadIdx.x;
    const int lane = t & 63;
    const int wv   = t >> 6;          // 0..15
    const int rg   = wv >> 3;         // 0..1
    const int cg   = wv & 7;          // 0..7
    const int ct0  = cg * 3;
    const int rb   = blockIdx.x >> 2;
    const int ks   = blockIdx.x & 3;
    const int row0 = rb * BM;

    // A staging: thread -> (row sr, 4 k's at k4) of each 128x32 slab
    const int sr = t >> 3;                // 0..127
    const int k4 = (t & 7) << 2;          // 0..28
    const float* xp = X + (size_t)(row0 + sr) * D_DIM + ks * 1024 + k4;
    const int awfrag = (sr >> 4) * 1024
                     + ((((k4 >> 3) << 4) | (sr & 15)) * 16) + ((k4 & 7) << 1);

    // B chunk assignment: waves 0-7 issue 2 chunks, waves 8-15 issue 1
    const int nB  = (wv < 8) ? 2 : 1;
    const int ch0 = (wv < 8) ? (wv * 2) : (wv + 8);
    const int slab0 = ks * 32;

    f32x4 acc00{}, acc01{}, acc02{}, acc10{}, acc11{}, acc12{},
          acc20{}, acc21{}, acc22{}, acc30{}, acc31{}, acc32{};
    float sinacc = 0.f;

#define STAGE(bufl, XV)                                                         \
    {                                                                           \
        sinacc += __sinf(XV.x) + __sinf(XV.y) + __sinf(XV.z) + __sinf(XV.w);    \
        uint2 h_;                                                               \
        h_.x = (unsigned)f2bf(XV.x) | ((unsigned)f2bf(XV.y) << 16);             \
        h_.y = (unsigned)f2bf(XV.z) | ((unsigned)f2bf(XV.w) << 16);             \
        *(uint2*)(pool + AOFF + (bufl) * 8192 + awfrag) = h_;                   \
    }

    // ---- prologue: B(0) -> buf0; X(0) staged; X(1) in flight ----
    {
        const unsigned short* g0 = W + (size_t)slab0 * 12288 + ch0 * 512 + lane * 8;
        gload16(g0, pool + BOFF + ch0 * 1024);
        if (nB == 2) gload16(g0 + 512, pool + BOFF + (ch0 + 1) * 1024);
    }
    f32x4 xn;
    {
        f32x4 x0 = *(const f32x4*)xp;
        STAGE(0, x0);
        xn = *(const f32x4*)(xp + 32);
    }
    asm volatile("s_waitcnt lgkmcnt(0)" ::: "memory");
    asm volatile("s_waitcnt vmcnt(1)" ::: "memory");   // B(0) landed; X(1) flying
    __builtin_amdgcn_s_barrier();
    __builtin_amdgcn_sched_barrier(0);

// BODY d: CUR = d&1 (literal), NXT = CUR^1.
#define BODY(d_, CUR, NXT)                                                      \
    {                                                                           \
        const int d__ = (d_);                                                   \
        if (d__ + 1 < NBODY) {                                                  \
            const unsigned short* g_ = W + (size_t)(slab0 + d__ + 1) * 12288    \
                                         + ch0 * 512 + lane * 8;                \
            gload16(g_, pool + BOFF + (NXT) * 24576 + ch0 * 1024);              \
            if (nB == 2)                                                        \
                gload16(g_ + 512, pool + BOFF + (NXT) * 24576 + (ch0 + 1) * 1024);\
        }                                                                       \
        int sl_ = d__ + 2; if (sl_ > NBODY - 1) sl_ = NBODY - 1;                \
        f32x4 xf_ = *(const f32x4*)(xp + (size_t)sl_ * 32);                     \
        if (d__ + 1 < NBODY) { STAGE(NXT, xn); }                                \
        xn = xf_;                                                               \
        const char* ab_ = pool + AOFF + (CUR) * 8192;                           \
        const char* bb_ = pool + BOFF + (CUR) * 24576;                          \
        s16x8 af0_ = *(const s16x8*)(ab_ + (rg * 4 + 0) * 1024 + lane * 16);    \
        s16x8 af1_ = *(const s16x8*)(ab_ + (rg * 4 + 1) * 1024 + lane * 16);    \
        s16x8 af2_ = *(const s16x8*)(ab_ + (rg * 4 + 2) * 1024 + lane * 16);    \
        s16x8 af3_ = *(const s16x8*)(ab_ + (rg * 4 + 3) * 1024 + lane * 16);    \
        s16x8 bf0_ = *(const s16x8*)(bb_ + (ct0 + 0) * 1024 + lane * 16);       \
        s16x8 bf1_ = *(const s16x8*)(bb_ + (ct0 + 1) * 1024 + lane * 16);       \
        s16x8 bf2_ = *(const s16x8*)(bb_ + (ct0 + 2) * 1024 + lane * 16);       \
        asm volatile("s_waitcnt lgkmcnt(0)" ::: "memory");                      \
        __builtin_amdgcn_sched_barrier(0);                                      \
        __builtin_amdgcn_s_setprio(1);                                          \
        acc00 = __builtin_amdgcn_mfma_f32_16x16x32_bf16(af0_, bf0_, acc00, 0, 0, 0); \
        acc01 = __builtin_amdgcn_mfma_f32_16x16x32_bf16(af0_, bf1_, acc01, 0, 0, 0); \
        acc02 = __builtin_amdgcn_mfma_f32_16x16x32_bf16(af0_, bf2_, acc02, 0, 0, 0); \
        acc10 = __builtin_amdgcn_mfma_f32_16x16x32_bf16(af1_, bf0_, acc10, 0, 0, 0); \
        acc11 = __builtin_amdgcn_mfma_f32_16x16x32_bf16(af1_, bf1_, acc11, 0, 0, 0); \
        acc12 = __builtin_amdgcn_mfma_f32_16x16x32_bf16(af1_, bf2_, acc12, 0, 0, 0); \
        acc20 = __builtin_amdgcn_mfma_f32_16x16x32_bf16(af2_, bf0_, acc20, 0, 0, 0); \
        acc21 = __builtin_amdgcn_mfma_f32_16x16x32_bf16(af2_, bf1_, acc21, 0, 0, 0); \
        acc22 = __builtin_amdgcn_mfma_f32_16x16x32_bf16(af2_, bf2_, acc22, 0, 0, 0); \
        acc30 = __builtin_amdgcn_mfma_f32_16x16x32_bf16(af3_, bf0_, acc30, 0, 0, 0); \
        acc31 = __builtin_amdgcn_mfma_f32_16x16x32_bf16(af3_, bf1_, acc31, 0, 0, 0); \
        acc32 = __builtin_amdgcn_mfma_f32_16x16x32_bf16(af3_, bf2_, acc32, 0, 0, 0); \
        __builtin_amdgcn_s_setprio(0);                                          \
        asm volatile("s_waitcnt vmcnt(1)" ::: "memory");                        \
        __builtin_amdgcn_s_barrier();                                           \
        __builtin_amdgcn_sched_barrier(0);                                      \
    }

    for (int d = 0; d < NBODY; d += 2) {
        BODY(d, 0, 1);
        BODY(d + 1, 1, 0);
    }
#undef BODY
#undef STAGE

    // ---- epilogue: f16 partial write + sin partial (no LDS, no syncs) ----
    _Float16* pb = part + (size_t)ks * 8192 * 384;
    const int lr4 = (lane >> 4) << 2;
    const int lc  = lane & 15;
    const f32x4 accA[4][3] = {{acc00, acc01, acc02}, {acc10, acc11, acc12},
                              {acc20, acc21, acc22}, {acc30, acc31, acc32}};
#pragma unroll
    for (int rf = 0; rf < 4; ++rf)
#pragma unroll
        for (int c = 0; c < 3; ++c) {
            const int col = (ct0 + c) * 16 + lc;
#pragma unroll
            for (int i = 0; i < 4; ++i) {
                const int rl = rg * 64 + rf * 16 + lr4 + i;
                pb[(size_t)(row0 + rl) * 384 + col] = (_Float16)accA[rf][c][i];
            }
        }

    sinacc += __shfl_xor(sinacc, 1);
    sinacc += __shfl_xor(sinacc, 2);
    sinacc += __shfl_xor(sinacc, 4);
    if ((t & 7) == 0)
        sinws[(size_t)ks * 8192 + row0 + sr] = sinacc;
}

// combine: sum 4 K-quarter partials, nonlinear terms + sin + beta -> out.
__global__ __launch_bounds__(512) void combine_kernel(const _Float16* __restrict__ part,
                                                      const float* __restrict__ sinws,
                                                      const float* __restrict__ C,
                                                      const float* __restrict__ beta,
                                                      const float* __restrict__ Csin,
                                                      float* __restrict__ out) {
    const int t   = threadIdx.x;
    const int row = blockIdx.x * 32 + (t >> 4);
    const int cc  = t & 15;
    const size_t rbase = (size_t)row * 384;

    float t1 = 0.f, t2 = 0.f, t3 = 0.f;
#pragma unroll
    for (int j = 0; j < 4; ++j) {
        const int c = j * 16 + cc;
        float a1 = 0.f, a2 = 0.f, b2 = 0.f, a3 = 0.f, b3 = 0.f, c3 = 0.f;
#pragma unroll
        for (int q = 0; q < 4; ++q) {
            const _Float16* p = part + (size_t)q * 8192 * 384 + rbase;
            a1 += (float)p[c];
            a2 += (float)p[64 + c];
            b2 += (float)p[128 + c];
            a3 += (float)p[192 + c];
            b3 += (float)p[256 + c];
            c3 += (float)p[320 + c];
        }
        t1 += a1;
        t2 += a2 * b2;
        t3 += a3 * b3 * c3;
    }
#pragma unroll
    for (int off = 1; off < 16; off <<= 1) {
        t1 += __shfl_xor(t1, off, 16);
        t2 += __shfl_xor(t2, off, 16);
        t3 += __shfl_xor(t3, off, 16);
    }
    if (cc == 0) {
        const float s = sinws[row] + sinws[8192 + row]
                      + sinws[2 * 8192 + row] + sinws[3 * 8192 + row];
        out[row] = beta[0] + C[0] * t1 + C[1] * t2 + C[2] * t3 + Csin[0] * s;
    }
}

extern "C" void kernel_launch(void* const* d_in, const int* in_sizes, int n_in,
                              void* d_out, int out_size, void* d_ws, size_t ws_size,
                              hipStream_t stream) {
    const float* X   = (const float*)d_in[0];
    const float* U1  = (const float*)d_in[1];
    const float* U2  = (const float*)d_in[2];
    const float* U3  = (const float*)d_in[3];
    const float* Cc  = (const float*)d_in[4];
    const float* bet = (const float*)d_in[5];
    const float* Cs  = (const float*)d_in[6];
    float* out = (float*)d_out;

    unsigned short* W = (unsigned short*)d_ws;                  // 3 MiB, frag-packed
    float* sinws = (float*)((char*)d_ws + SINW_OFF);            // 128 KiB
    _Float16* part = (_Float16*)((char*)d_ws + PART_OFF);       // 24 MiB

    reg_init_kernel<<<1, 64, 0, stream>>>(Cc, Cs, out + 8192);
    build_w_kernel<<<128 * NT, 64, 0, stream>>>(U1, U2, U3, W, out + 8192);
    poly_main_kernel<<<256, 1024, 0, stream>>>(X, W, part, sinws);
    combine_kernel<<<256, 512, 0, stream>>>(part, sinws, Cc, bet, Cs, out);
}